// Round 5
// baseline (587.471 us; speedup 1.0000x reference)
//
#include <hip/hip_runtime.h>
#include <hip/hip_bf16.h>
#include <math.h>

// Problem constants (B=4,S=1024,D=1024,H=4096,E=8,K=2)
#define TOKENS 4096
#define DD 1024
#define HH 4096
#define NE 8
#define PAIRS 8192     // TOKENS * K
#define ROWCAP 8448    // PAIRS + 256 slack for tile overread
#define T1CAP 40       // max sum ceil(n_e/256) = 39
#define T2CAP 72       // max sum ceil(n_e/128) = 71
#define G1_NT 16       // gemm1 K-tiles (1024/64)
#define G2_NT 32       // gemm2 K-tiles per K-half (2048/64)

typedef __bf16 bf16x8 __attribute__((ext_vector_type(8)));
typedef float f32x4 __attribute__((ext_vector_type(4)));

__device__ __forceinline__ unsigned short f2bf(float f) {
  union { float f; unsigned int u; } c; c.f = f;
  unsigned int x = c.u;
  return (unsigned short)((x + 0x7fffu + ((x >> 16) & 1u)) >> 16);  // RNE
}

__device__ __forceinline__ void lds16(void* l, const void* g) {
  __builtin_amdgcn_global_load_lds((const __attribute__((address_space(1))) void*)g,
                                   (__attribute__((address_space(3))) void*)l, 16, 0, 0);
}

// ---------------- init ----------------
__global__ void init_kernel(int* counts) {
  if (threadIdx.x < NE) counts[threadIdx.x] = 0;
}

// ---------------- transpose+convert: [E][R][C] f32 -> [E][C][R] bf16 ----------------
__global__ __launch_bounds__(256) void transpose_kernel(const float* __restrict__ in,
                                                        unsigned short* __restrict__ out,
                                                        int R, int C) {
  int ntr = R >> 6, ntc = C >> 6;
  int per_e = ntr * ntc;
  int b = blockIdx.x;
  int e = b / per_e;
  int rem = b - e * per_e;
  int tr = rem / ntc, tc = rem - (rem / ntc) * ntc;
  const float* ie = in + (size_t)e * R * C;
  unsigned short* oe = out + (size_t)e * R * C;

  __shared__ float t[64][68];
  int tid = threadIdx.x;
  int lr = tid >> 2;
  int c4 = (tid & 3) << 4;
  const float* src = ie + (size_t)(tr * 64 + lr) * C + tc * 64 + c4;
  float4 v0 = *(const float4*)(src);
  float4 v1 = *(const float4*)(src + 4);
  float4 v2 = *(const float4*)(src + 8);
  float4 v3 = *(const float4*)(src + 12);
  *(float4*)&t[lr][c4] = v0;
  *(float4*)&t[lr][c4 + 4] = v1;
  *(float4*)&t[lr][c4 + 8] = v2;
  *(float4*)&t[lr][c4 + 12] = v3;
  __syncthreads();

  int oc = tid >> 2;
  int r0 = (tid & 3) << 4;
  unsigned int pk[8];
#pragma unroll
  for (int i = 0; i < 8; i++) {
    unsigned int lo = f2bf(t[r0 + 2 * i][oc]);
    unsigned int hi = f2bf(t[r0 + 2 * i + 1][oc]);
    pk[i] = lo | (hi << 16);
  }
  unsigned short* dst = oe + (size_t)(tc * 64 + oc) * R + tr * 64 + r0;
  *(uint4*)(dst) = make_uint4(pk[0], pk[1], pk[2], pk[3]);
  *(uint4*)(dst + 8) = make_uint4(pk[4], pk[5], pk[6], pk[7]);
}

// ---------------- gate ----------------
__global__ __launch_bounds__(256) void gate_kernel(const float* __restrict__ x,
    const float* __restrict__ Wg, const float* __restrict__ bg,
    int* __restrict__ counts, int* __restrict__ tok_e, int* __restrict__ tok_slot,
    float* __restrict__ tok_w) {
  int t = blockIdx.x, tid = threadIdx.x;
  const float* xr = x + (size_t)t * DD;
  float p[8] = {0, 0, 0, 0, 0, 0, 0, 0};
  for (int d = tid; d < DD; d += 256) {
    float xv = xr[d];
    const float4* wrow = (const float4*)(Wg + (size_t)d * NE);
    float4 w0 = wrow[0], w1 = wrow[1];
    p[0] += xv * w0.x; p[1] += xv * w0.y; p[2] += xv * w0.z; p[3] += xv * w0.w;
    p[4] += xv * w1.x; p[5] += xv * w1.y; p[6] += xv * w1.z; p[7] += xv * w1.w;
  }
#pragma unroll
  for (int e = 0; e < 8; e++) {
    p[e] += __shfl_down(p[e], 32);
    p[e] += __shfl_down(p[e], 16);
    p[e] += __shfl_down(p[e], 8);
    p[e] += __shfl_down(p[e], 4);
    p[e] += __shfl_down(p[e], 2);
    p[e] += __shfl_down(p[e], 1);
  }
  __shared__ float red[4][8];
  if ((tid & 63) == 0) {
#pragma unroll
    for (int e = 0; e < 8; e++) red[tid >> 6][e] = p[e];
  }
  __syncthreads();
  if (tid == 0) {
    float l[8];
#pragma unroll
    for (int e = 0; e < 8; e++) l[e] = red[0][e] + red[1][e] + red[2][e] + red[3][e] + bg[e];
    int e0 = 0; float l0 = l[0];
    for (int e = 1; e < 8; e++) if (l[e] > l0) { e0 = e; l0 = l[e]; }
    int e1 = -1; float l1 = -3.4e38f;
    for (int e = 0; e < 8; e++) if (e != e0 && l[e] > l1) { e1 = e; l1 = l[e]; }
    float w0 = 1.f / (1.f + __expf(l1 - l0));
    float w1 = 1.f - w0;
    int s0 = atomicAdd(&counts[e0], 1);
    int s1 = atomicAdd(&counts[e1], 1);
    tok_e[2 * t] = e0;     tok_slot[2 * t] = s0;     tok_w[2 * t] = w0;
    tok_e[2 * t + 1] = e1; tok_slot[2 * t + 1] = s1; tok_w[2 * t + 1] = w1;
  }
}

// ---------------- scan: expert offsets + two tile maps (256-row, 128-row) ----------------
__global__ void scan_kernel(const int* __restrict__ counts, int* __restrict__ offsets,
                            int* __restrict__ tm1_e, int* __restrict__ tm1_row0,
                            int* __restrict__ tm1_nrow, int* __restrict__ ntp1,
                            int* __restrict__ tm2_e, int* __restrict__ tm2_row0,
                            int* __restrict__ tm2_nrow, int* __restrict__ ntp2) {
  if (threadIdx.x != 0 || blockIdx.x != 0) return;
  int c[NE];
#pragma unroll
  for (int e = 0; e < NE; e++) c[e] = counts[e];
  int off = 0, n1 = 0, n2 = 0;
  for (int e = 0; e < NE; e++) {
    offsets[e] = off;
    for (int r = 0; r < c[e]; r += 256) {
      tm1_e[n1] = e; tm1_row0[n1] = off + r;
      tm1_nrow[n1] = (c[e] - r < 256) ? (c[e] - r) : 256;
      n1++;
    }
    for (int r = 0; r < c[e]; r += 128) {
      tm2_e[n2] = e; tm2_row0[n2] = off + r;
      tm2_nrow[n2] = (c[e] - r < 128) ? (c[e] - r) : 128;
      n2++;
    }
    off += c[e];
  }
  *ntp1 = n1;
  *ntp2 = n2;
}

// ---------------- gather ----------------
__global__ __launch_bounds__(64) void gather_kernel(const float* __restrict__ x,
    const int* __restrict__ tok_e, const int* __restrict__ tok_slot,
    const float* __restrict__ tok_w, const int* __restrict__ offsets,
    unsigned short* __restrict__ Xe, int* __restrict__ pair_row, float* __restrict__ rw) {
  int pp = blockIdx.x, tid = threadIdx.x;
  int e = tok_e[pp];
  int row = offsets[e] + tok_slot[pp];
  int t = pp >> 1;
  const float* src = x + (size_t)t * DD + tid * 16;
  float4 v0 = *(const float4*)(src);
  float4 v1 = *(const float4*)(src + 4);
  float4 v2 = *(const float4*)(src + 8);
  float4 v3 = *(const float4*)(src + 12);
  unsigned int pk[8];
  pk[0] = f2bf(v0.x) | ((unsigned int)f2bf(v0.y) << 16);
  pk[1] = f2bf(v0.z) | ((unsigned int)f2bf(v0.w) << 16);
  pk[2] = f2bf(v1.x) | ((unsigned int)f2bf(v1.y) << 16);
  pk[3] = f2bf(v1.z) | ((unsigned int)f2bf(v1.w) << 16);
  pk[4] = f2bf(v2.x) | ((unsigned int)f2bf(v2.y) << 16);
  pk[5] = f2bf(v2.z) | ((unsigned int)f2bf(v2.w) << 16);
  pk[6] = f2bf(v3.x) | ((unsigned int)f2bf(v3.y) << 16);
  pk[7] = f2bf(v3.z) | ((unsigned int)f2bf(v3.w) << 16);
  unsigned short* dst = Xe + (size_t)row * DD + tid * 16;
  *(uint4*)(dst) = make_uint4(pk[0], pk[1], pk[2], pk[3]);
  *(uint4*)(dst + 8) = make_uint4(pk[4], pk[5], pk[6], pk[7]);
  if (tid == 0) { pair_row[pp] = row; rw[row] = tok_w[pp]; }
}

// ================= GEMM1: 4-phase schedule, precomputed offsets =================
// BM=256, BN=128 dual (Wa,W1), BK=64, 512 thr (8 waves 2Mx4N), 128KB LDS dbuf.
// Buf region 64KB: A (slots0-1 contiguous, rows 0..255) @0, Wa @32768, W1 @49152.
__global__ __launch_bounds__(512, 2) void gemm1_kernel(
    const unsigned short* __restrict__ Xe,
    const unsigned short* __restrict__ WaT,   // [E][H][D] bf16
    const unsigned short* __restrict__ W1T,
    const float* __restrict__ ba, const float* __restrict__ b1,
    unsigned short* __restrict__ h,
    const int* __restrict__ tm_e, const int* __restrict__ tm_row0,
    const int* __restrict__ tm_nrow, const int* __restrict__ ntp) {
  __shared__ unsigned short sm[8][8192];

  int work = blockIdx.x;
  int tile = work >> 5;
  if (tile >= *ntp) return;
  int n0 = (work & 31) << 7;
  int e = tm_e[tile], row0 = tm_row0[tile], nrow = tm_nrow[tile];

  int tid = threadIdx.x;
  int lane = tid & 63, wid = tid >> 6;
  int wm = wid >> 2, wn = wid & 3;     // 2M x 4N
  int fr = lane & 15, kc = lane >> 4;

  int srow = tid >> 3;
  int sx0 = (((tid & 7) ^ (srow & 7)) << 3);   // pre-swizzled source chunk

  // running global staging pointers (advance +64 elem per stage of that slot)
  const unsigned short* pA0 = Xe + (size_t)(row0 + srow) * DD + sx0;
  const unsigned short* pA1 = Xe + (size_t)(row0 + 128 + srow) * DD + sx0;
  const unsigned short* pBa = WaT + ((size_t)e << 22) + (size_t)(n0 + srow) * DD + sx0;
  const unsigned short* pBu = W1T + ((size_t)e << 22) + (size_t)(n0 + srow) * DD + sx0;

  char* lb = (char*)&sm[0][0];
  unsigned short* ldst = &sm[0][0] + (size_t)tid * 8;  // + slot*8192 + buf*32768 (shorts)

  auto stg2 = [&](int buf, int slot, const unsigned short*& ptr) {
    unsigned short* L = ldst + ((buf << 2) | slot) * 8192;
    lds16(L, ptr);
    lds16(L + 4096, ptr + (size_t)64 * DD);
    ptr += 64;
  };

  // precomputed swizzled LDS read offsets (bytes, within 64KB buf region)
  int aof[2][4][2], bof[2][2];
#pragma unroll
  for (int mh = 0; mh < 2; mh++)
#pragma unroll
    for (int m = 0; m < 4; m++)
#pragma unroll
      for (int ks = 0; ks < 2; ks++) {
        int R = wm * 128 + mh * 64 + m * 16 + fr;           // 0..255 (A slots contiguous)
        aof[mh][m][ks] = R * 128 + ((((ks << 2) | kc) ^ (R & 7)) << 4);
      }
#pragma unroll
  for (int n = 0; n < 2; n++)
#pragma unroll
    for (int ks = 0; ks < 2; ks++) {
      int rB = wn * 32 + n * 16 + fr;
      bof[n][ks] = 32768 + rB * 128 + ((((ks << 2) | kc) ^ (rB & 7)) << 4);
    }

  f32x4 accA[8][2], accU[8][2];
  f32x4 z = {0.f, 0.f, 0.f, 0.f};
#pragma unroll
  for (int m = 0; m < 8; m++)
#pragma unroll
    for (int n = 0; n < 2; n++) { accA[m][n] = z; accU[m][n] = z; }

  // prologue: T0.{Wa,W1,A0,A1}, T1.{Wa,W1,A0}; certify T0 (6 newest = T1's)
  stg2(0, 2, pBa); stg2(0, 3, pBu); stg2(0, 0, pA0); stg2(0, 1, pA1);
  stg2(1, 2, pBa); stg2(1, 3, pBu); stg2(1, 0, pA0);
  asm volatile("s_waitcnt vmcnt(6)" ::: "memory");
  __builtin_amdgcn_s_barrier();

  for (int T = 0; T < G1_NT; ++T) {
    int buf = T & 1, nbuf = buf ^ 1;
    const char* lbb = lb + (buf << 16);
    bf16x8 a[4][2], bA[2][2], bU[2][2];
    // ---- P1: read a(mh0)+bA; stage (T+1).A1 into other buf ----
#pragma unroll
    for (int m = 0; m < 4; m++)
#pragma unroll
      for (int ks = 0; ks < 2; ks++)
        a[m][ks] = *(const bf16x8*)(lbb + aof[0][m][ks]);
#pragma unroll
    for (int n = 0; n < 2; n++)
#pragma unroll
      for (int ks = 0; ks < 2; ks++)
        bA[n][ks] = *(const bf16x8*)(lbb + bof[n][ks]);
    stg2(nbuf, 1, pA1);
    __builtin_amdgcn_s_barrier();
    asm volatile("s_waitcnt lgkmcnt(0)" ::: "memory");
    __builtin_amdgcn_s_setprio(1);
#pragma unroll
    for (int ks = 0; ks < 2; ks++)
#pragma unroll
      for (int m = 0; m < 4; m++)
#pragma unroll
        for (int n = 0; n < 2; n++)
          accA[m][n] = __builtin_amdgcn_mfma_f32_16x16x32_bf16(a[m][ks], bA[n][ks], accA[m][n], 0, 0, 0);
    __builtin_amdgcn_s_setprio(0);
    __builtin_amdgcn_s_barrier();
    // ---- P2: read bU; stage (T+2).Wa (cur buf; readers retired) ----
#pragma unroll
    for (int n = 0; n < 2; n++)
#pragma unroll
      for (int ks = 0; ks < 2; ks++)
        bU[n][ks] = *(const bf16x8*)(lbb + bof[n][ks] + 16384);
    stg2(buf, 2, pBa);
    __builtin_amdgcn_s_barrier();
    asm volatile("s_waitcnt lgkmcnt(0)" ::: "memory");
    __builtin_amdgcn_s_setprio(1);
#pragma unroll
    for (int ks = 0; ks < 2; ks++)
#pragma unroll
      for (int m = 0; m < 4; m++)
#pragma unroll
        for (int n = 0; n < 2; n++)
          accU[m][n] = __builtin_amdgcn_mfma_f32_16x16x32_bf16(a[m][ks], bU[n][ks], accU[m][n], 0, 0, 0);
    __builtin_amdgcn_s_setprio(0);
    __builtin_amdgcn_s_barrier();
    // ---- P3: read a(mh1); stage (T+2).W1 ----
#pragma unroll
    for (int m = 0; m < 4; m++)
#pragma unroll
      for (int ks = 0; ks < 2; ks++)
        a[m][ks] = *(const bf16x8*)(lbb + aof[1][m][ks]);
    stg2(buf, 3, pBu);
    __builtin_amdgcn_s_barrier();
    asm volatile("s_waitcnt lgkmcnt(0)" ::: "memory");
    __builtin_amdgcn_s_setprio(1);
#pragma unroll
    for (int ks = 0; ks < 2; ks++)
#pragma unroll
      for (int m = 0; m < 4; m++)
#pragma unroll
        for (int n = 0; n < 2; n++)
          accA[4 + m][n] = __builtin_amdgcn_mfma_f32_16x16x32_bf16(a[m][ks], bA[n][ks], accA[4 + m][n], 0, 0, 0);
    __builtin_amdgcn_s_setprio(0);
    __builtin_amdgcn_s_barrier();
    // ---- P4: stage (T+2).A0; MFMA(mh1,U); vmcnt(6) certifies T+1 ----
    stg2(buf, 0, pA0);
    __builtin_amdgcn_s_barrier();
    __builtin_amdgcn_s_setprio(1);
#pragma unroll
    for (int ks = 0; ks < 2; ks++)
#pragma unroll
      for (int m = 0; m < 4; m++)
#pragma unroll
        for (int n = 0; n < 2; n++)
          accU[4 + m][n] = __builtin_amdgcn_mfma_f32_16x16x32_bf16(a[m][ks], bU[n][ks], accU[4 + m][n], 0, 0, 0);
    __builtin_amdgcn_s_setprio(0);
    asm volatile("s_waitcnt vmcnt(6)" ::: "memory");
    __builtin_amdgcn_s_barrier();
  }

  // epilogue: SwiGLU -> bf16 h
  int lr4 = kc * 4;
#pragma unroll
  for (int n = 0; n < 2; n++) {
    int col = n0 + wn * 32 + n * 16 + fr;
    float bav = ba[e * HH + col];
    float buv = b1[e * HH + col];
#pragma unroll
    for (int m = 0; m < 8; m++) {
#pragma unroll
      for (int j = 0; j < 4; j++) {
        int r = wm * 128 + m * 16 + lr4 + j;
        if (r < nrow) {
          float av = accA[m][n][j] + bav;
          float uv = accU[m][n][j] + buv;
          float s = __builtin_amdgcn_rcpf(1.f + __expf(-av));
          h[(size_t)(row0 + r) * HH + col] = f2bf(av * s * uv);
        }
      }
    }
  }
}

// ================= GEMM2: 2-phase schedule, K-split=2, precomputed offsets =================
// BM=128, BN=256, BK=64, 512 thr (8 waves 2Mx4N, per-wave 64x64).
// A dbuf (2x16KB) + B triple-buffer (3x32KB) = 128KB.
__global__ __launch_bounds__(512, 2) void gemm2_kernel(
    const unsigned short* __restrict__ hb,
    const unsigned short* __restrict__ W2T,   // [E][D][H] bf16
    const float* __restrict__ b2, const float* __restrict__ rw,
    float* __restrict__ contribA, float* __restrict__ contribB,
    const int* __restrict__ tm_e, const int* __restrict__ tm_row0,
    const int* __restrict__ tm_nrow, const int* __restrict__ ntp) {
  __shared__ unsigned short smA[2][8192];    // [parity][128*64]
  __shared__ unsigned short smB[3][16384];   // [t%3][256*64]

  int work = blockIdx.x;
  int tile = work >> 3;
  if (tile >= *ntp) return;
  int rem = work & 7;
  int n0 = (rem >> 1) << 8;   // 0,256,512,768
  int kh = rem & 1;
  int e = tm_e[tile], row0 = tm_row0[tile], nrow = tm_nrow[tile];

  int tid = threadIdx.x;
  int lane = tid & 63, wid = tid >> 6;
  int wm = wid >> 2, wn = wid & 3;     // 2M x 4N
  int fr = lane & 15, kc = lane >> 4;

  int srow = tid >> 3;
  int sx0 = (((tid & 7) ^ (srow & 7)) << 3);

  const unsigned short* pA = hb + (size_t)(row0 + srow) * HH + kh * 2048 + sx0;
  const unsigned short* pB = W2T + ((size_t)e << 22) + (size_t)(n0 + srow) * HH + kh * 2048 + sx0;

  char* lbA = (char*)&smA[0][0];
  char* lbB = (char*)&smB[0][0];
  unsigned short* ldA = &smA[0][0] + (size_t)tid * 8;
  unsigned short* ldB = &smB[0][0] + (size_t)tid * 8;

  auto stgA = [&](int par) {
    unsigned short* L = ldA + par * 8192;
    lds16(L, pA);
    lds16(L + 4096, pA + (size_t)64 * HH);
    pA += 64;
  };
  auto stgB = [&](int slot) {
    unsigned short* L = ldB + slot * 16384;
    lds16(L, pB);
    lds16(L + 4096, pB + (size_t)64 * HH);
    lds16(L + 8192, pB + (size_t)128 * HH);
    lds16(L + 12288, pB + (size_t)192 * HH);
    pB += 64;
  };

  int aofs[4][2], bofs[4][2];
#pragma unroll
  for (int m = 0; m < 4; m++)
#pragma unroll
    for (int ks = 0; ks < 2; ks++) {
      int r = wm * 64 + m * 16 + fr;                 // 0..127
      aofs[m][ks] = r * 128 + ((((ks << 2) | kc) ^ (r & 7)) << 4);
    }
#pragma unroll
  for (int n = 0; n < 4; n++)
#pragma unroll
    for (int ks = 0; ks < 2; ks++) {
      int rb = wn * 64 + n * 16 + fr;                // 0..255
      bofs[n][ks] = rb * 128 + ((((ks << 2) | kc) ^ (rb & 7)) << 4);
    }

  f32x4 acc[4][4];
  f32x4 z = {0.f, 0.f, 0.f, 0.f};
#pragma unroll
  for (int m = 0; m < 4; m++)
#pragma unroll
    for (int n = 0; n < 4; n++) acc[m][n] = z;

  // prologue: B0,A0,B1,A1 (12 loads); certify T0
  stgB(0); stgA(0); stgB(1); stgA(1);
  asm volatile("s_waitcnt vmcnt(6)" ::: "memory");
  __builtin_amdgcn_s_barrier();

  for (int T = 0; T < G2_NT; ++T) {
    int par = T & 1, slB = T % 3;
    const char* lA = lbA + (par << 14);
    const char* lB = lbB + (slB << 15);
    bf16x8 a[4][2], b[4][2];
    // ---- P1: read all a + b(n0,n1); stage B(T+2) ----
#pragma unroll
    for (int m = 0; m < 4; m++)
#pragma unroll
      for (int ks = 0; ks < 2; ks++)
        a[m][ks] = *(const bf16x8*)(lA + aofs[m][ks]);
#pragma unroll
    for (int n = 0; n < 2; n++)
#pragma unroll
      for (int ks = 0; ks < 2; ks++)
        b[n][ks] = *(const bf16x8*)(lB + bofs[n][ks]);
    stgB((T + 2) % 3);
    __builtin_amdgcn_s_barrier();
    asm volatile("s_waitcnt lgkmcnt(0)" ::: "memory");
    __builtin_amdgcn_s_setprio(1);
#pragma unroll
    for (int ks = 0; ks < 2; ks++)
#pragma unroll
      for (int m = 0; m < 4; m++)
#pragma unroll
        for (int n = 0; n < 2; n++)
          acc[m][n] = __builtin_amdgcn_mfma_f32_16x16x32_bf16(a[m][ks], b[n][ks], acc[m][n], 0, 0, 0);
    __builtin_amdgcn_s_setprio(0);
    __builtin_amdgcn_s_barrier();
    // ---- P2: read b(n2,n3); stage A(T+2) (cur parity; readers retired) ----
#pragma unroll
    for (int n = 2; n < 4; n++)
#pragma unroll
      for (int ks = 0; ks < 2; ks++)
        b[n][ks] = *(const bf16x8*)(lB + bofs[n][ks]);
    stgA(par);
    __builtin_amdgcn_s_barrier();
    asm volatile("s_waitcnt lgkmcnt(0)" ::: "memory");
    __builtin_amdgcn_s_setprio(1);
#pragma unroll
    for (int ks = 0; ks < 2; ks++)
#pragma unroll
      for (int m = 0; m < 4; m++)
#pragma unroll
        for (int n = 2; n < 4; n++)
          acc[m][n] = __builtin_amdgcn_mfma_f32_16x16x32_bf16(a[m][ks], b[n][ks], acc[m][n], 0, 0, 0);
    __builtin_amdgcn_s_setprio(0);
    asm volatile("s_waitcnt vmcnt(6)" ::: "memory");
    __builtin_amdgcn_s_barrier();
  }

  float b2v[4];
#pragma unroll
  for (int n = 0; n < 4; n++)
    b2v[n] = (kh == 0) ? b2[e * DD + n0 + wn * 64 + n * 16 + fr] : 0.f;
  float* cbuf = kh ? contribB : contribA;
  int lr4 = kc * 4;
#pragma unroll
  for (int m = 0; m < 4; m++) {
#pragma unroll
    for (int j = 0; j < 4; j++) {
      int r = wm * 64 + m * 16 + lr4 + j;
      if (r < nrow) {
        float wv = rw[row0 + r];
        float* dst = cbuf + (size_t)(row0 + r) * DD + n0 + wn * 64 + fr;
#pragma unroll
        for (int n = 0; n < 4; n++)
          dst[n * 16] = wv * (acc[m][n][j] + b2v[n]);
      }
    }
  }
}

// ---------------- combine ----------------
__global__ __launch_bounds__(256) void combine_kernel(const float* __restrict__ cA,
    const float* __restrict__ cB, const int* __restrict__ pair_row,
    float* __restrict__ out) {
  int t = blockIdx.x, tid = threadIdx.x;
  int r0 = pair_row[2 * t], r1 = pair_row[2 * t + 1];
  const float4* a0 = (const float4*)(cA + (size_t)r0 * DD);
  const float4* b0 = (const float4*)(cB + (size_t)r0 * DD);
  const float4* a1 = (const float4*)(cA + (size_t)r1 * DD);
  const float4* b1 = (const float4*)(cB + (size_t)r1 * DD);
  float4* o = (float4*)(out + (size_t)t * DD);
  float4 x0 = a0[tid], y0 = b0[tid], x1 = a1[tid], y1 = b1[tid];
  o[tid] = make_float4((x0.x + y0.x) + (x1.x + y1.x),
                       (x0.y + y0.y) + (x1.y + y1.y),
                       (x0.z + y0.z) + (x1.z + y1.z),
                       (x0.w + y0.w) + (x1.w + y1.w));
}

extern "C" void kernel_launch(void* const* d_in, const int* in_sizes, int n_in,
                              void* d_out, int out_size, void* d_ws, size_t ws_size,
                              hipStream_t stream) {
  const float* x  = (const float*)d_in[0];
  const float* Wg = (const float*)d_in[1];
  const float* bg = (const float*)d_in[2];
  const float* W1 = (const float*)d_in[3];
  const float* b1 = (const float*)d_in[4];
  const float* Wa = (const float*)d_in[5];
  const float* ba = (const float*)d_in[6];
  const float* W2 = (const float*)d_in[7];
  const float* b2 = (const float*)d_in[8];
  float* out = (float*)d_out;
  (void)in_sizes; (void)n_in; (void)out_size; (void)ws_size;

  char* p = (char*)d_ws;
  auto take = [&](size_t bytes) { char* r = p; p += (bytes + 255) & ~(size_t)255; return r; };
  unsigned short* WaT = (unsigned short*)take((size_t)NE * HH * DD * 2);
  unsigned short* W1T = (unsigned short*)take((size_t)NE * HH * DD * 2);
  unsigned short* W2T = (unsigned short*)take((size_t)NE * DD * HH * 2);
  unsigned short* Xe  = (unsigned short*)take((size_t)ROWCAP * DD * 2);
  unsigned short* hb  = (unsigned short*)take((size_t)ROWCAP * HH * 2);
  float* contribA     = (float*)take((size_t)ROWCAP * DD * 4);
  int* counts   = (int*)take(64);
  int* offsets  = (int*)take(64);
  int* tok_e    = (int*)take(PAIRS * 4);
  int* tok_slot = (int*)take(PAIRS * 4);
  float* tok_w  = (float*)take(PAIRS * 4);
  int* pair_row = (int*)take(PAIRS * 4);
  float* rw     = (float*)take(ROWCAP * 4);
  int* tm1_e    = (int*)take(T1CAP * 4);
  int* tm1_row0 = (int*)take(T1CAP * 4);
  int* tm1_nrow = (int*)take(T1CAP * 4);
  int* ntp1     = (int*)take(64);
  int* tm2_e    = (int*)take(T2CAP * 4);
  int* tm2_row0 = (int*)take(T2CAP * 4);
  int* tm2_nrow = (int*)take(T2CAP * 4);
  int* ntp2     = (int*)take(64);
  // contribB aliases WaT (dead after gemm1; stream-ordered)
  float* contribB = (float*)WaT;

  init_kernel<<<1, 64, 0, stream>>>(counts);
  transpose_kernel<<<NE * 16 * 64, 256, 0, stream>>>(Wa, WaT, DD, HH);
  transpose_kernel<<<NE * 16 * 64, 256, 0, stream>>>(W1, W1T, DD, HH);
  transpose_kernel<<<NE * 64 * 16, 256, 0, stream>>>(W2, W2T, HH, DD);
  gate_kernel<<<TOKENS, 256, 0, stream>>>(x, Wg, bg, counts, tok_e, tok_slot, tok_w);
  scan_kernel<<<1, 64, 0, stream>>>(counts, offsets, tm1_e, tm1_row0, tm1_nrow, ntp1,
                                    tm2_e, tm2_row0, tm2_nrow, ntp2);
  gather_kernel<<<PAIRS, 64, 0, stream>>>(x, tok_e, tok_slot, tok_w, offsets, Xe, pair_row, rw);
  gemm1_kernel<<<T1CAP * 32, 512, 0, stream>>>(Xe, WaT, W1T, ba, b1, hb, tm1_e, tm1_row0, tm1_nrow, ntp1);
  gemm2_kernel<<<T2CAP * 8, 512, 0, stream>>>(hb, W2T, b2, rw, contribA, contribB, tm2_e, tm2_row0, tm2_nrow, ntp2);
  combine_kernel<<<TOKENS, 256, 0, stream>>>(contribA, contribB, pair_row, out);
}

// Round 7
// 556.757 us; speedup vs baseline: 1.0552x; 1.0552x over previous
//
#include <hip/hip_runtime.h>
#include <hip/hip_bf16.h>
#include <math.h>

// Problem constants (B=4,S=1024,D=1024,H=4096,E=8,K=2)
#define TOKENS 4096
#define DD 1024
#define HH 4096
#define NE 8
#define PAIRS 8192     // TOKENS * K
#define ROWCAP 8448    // PAIRS + slack for tile overread
#define TCAP 72        // max sum ceil(n_e/128) = 71
#define G1_NT 32       // gemm1 K-steps (1024/32)
#define G2_NT 128      // gemm2 K-steps (4096/32)  -- r6 bug: was 64 (half the K-sum)

typedef __bf16 bf16x8 __attribute__((ext_vector_type(8)));
typedef float f32x4 __attribute__((ext_vector_type(4)));

__device__ __forceinline__ unsigned short f2bf(float f) {
  union { float f; unsigned int u; } c; c.f = f;
  unsigned int x = c.u;
  return (unsigned short)((x + 0x7fffu + ((x >> 16) & 1u)) >> 16);  // RNE
}

__device__ __forceinline__ void lds16(void* l, const void* g) {
  __builtin_amdgcn_global_load_lds((const __attribute__((address_space(1))) void*)g,
                                   (__attribute__((address_space(3))) void*)l, 16, 0, 0);
}

// ---------------- init ----------------
__global__ void init_kernel(int* counts) {
  if (threadIdx.x < NE) counts[threadIdx.x] = 0;
}

// ---------------- fused transpose+convert: 3 weights in one launch ----------------
// section 0: Wa[E][D][H]->WaT[E][H][D]; 1: W1->W1T; 2: W2[E][H][D]->W2T[E][D][H]
__global__ __launch_bounds__(256) void transpose_kernel(
    const float* __restrict__ Wa, const float* __restrict__ W1, const float* __restrict__ W2,
    unsigned short* __restrict__ WaT, unsigned short* __restrict__ W1T,
    unsigned short* __restrict__ W2T) {
  int b = blockIdx.x;
  int sec = b >> 13;              // 8192 blocks per section
  int sb = b & 8191;
  const float* in; unsigned short* out; int R, C;
  if (sec == 0)      { in = Wa; out = WaT; R = DD; C = HH; }
  else if (sec == 1) { in = W1; out = W1T; R = DD; C = HH; }
  else               { in = W2; out = W2T; R = HH; C = DD; }
  int ntr = R >> 6, ntc = C >> 6;
  int per_e = ntr * ntc;
  int e = sb / per_e;
  int rem = sb - e * per_e;
  int tr = rem / ntc, tc = rem - (rem / ntc) * ntc;
  const float* ie = in + (size_t)e * R * C;
  unsigned short* oe = out + (size_t)e * R * C;

  __shared__ float t[64][68];
  int tid = threadIdx.x;
  int lr = tid >> 2;
  int c4 = (tid & 3) << 4;
  const float* src = ie + (size_t)(tr * 64 + lr) * C + tc * 64 + c4;
  float4 v0 = *(const float4*)(src);
  float4 v1 = *(const float4*)(src + 4);
  float4 v2 = *(const float4*)(src + 8);
  float4 v3 = *(const float4*)(src + 12);
  *(float4*)&t[lr][c4] = v0;
  *(float4*)&t[lr][c4 + 4] = v1;
  *(float4*)&t[lr][c4 + 8] = v2;
  *(float4*)&t[lr][c4 + 12] = v3;
  __syncthreads();

  int oc = tid >> 2;
  int r0 = (tid & 3) << 4;
  unsigned int pk[8];
#pragma unroll
  for (int i = 0; i < 8; i++) {
    unsigned int lo = f2bf(t[r0 + 2 * i][oc]);
    unsigned int hi = f2bf(t[r0 + 2 * i + 1][oc]);
    pk[i] = lo | (hi << 16);
  }
  unsigned short* dst = oe + (size_t)(tc * 64 + oc) * R + tr * 64 + r0;
  *(uint4*)(dst) = make_uint4(pk[0], pk[1], pk[2], pk[3]);
  *(uint4*)(dst + 8) = make_uint4(pk[4], pk[5], pk[6], pk[7]);
}

// ---------------- gate ----------------
__global__ __launch_bounds__(256) void gate_kernel(const float* __restrict__ x,
    const float* __restrict__ Wg, const float* __restrict__ bg,
    int* __restrict__ counts, int* __restrict__ tok_e, int* __restrict__ tok_slot,
    float* __restrict__ tok_w) {
  int t = blockIdx.x, tid = threadIdx.x;
  const float* xr = x + (size_t)t * DD;
  float p[8] = {0, 0, 0, 0, 0, 0, 0, 0};
  for (int d = tid; d < DD; d += 256) {
    float xv = xr[d];
    const float4* wrow = (const float4*)(Wg + (size_t)d * NE);
    float4 w0 = wrow[0], w1 = wrow[1];
    p[0] += xv * w0.x; p[1] += xv * w0.y; p[2] += xv * w0.z; p[3] += xv * w0.w;
    p[4] += xv * w1.x; p[5] += xv * w1.y; p[6] += xv * w1.z; p[7] += xv * w1.w;
  }
#pragma unroll
  for (int e = 0; e < 8; e++) {
    p[e] += __shfl_down(p[e], 32);
    p[e] += __shfl_down(p[e], 16);
    p[e] += __shfl_down(p[e], 8);
    p[e] += __shfl_down(p[e], 4);
    p[e] += __shfl_down(p[e], 2);
    p[e] += __shfl_down(p[e], 1);
  }
  __shared__ float red[4][8];
  if ((tid & 63) == 0) {
#pragma unroll
    for (int e = 0; e < 8; e++) red[tid >> 6][e] = p[e];
  }
  __syncthreads();
  if (tid == 0) {
    float l[8];
#pragma unroll
    for (int e = 0; e < 8; e++) l[e] = red[0][e] + red[1][e] + red[2][e] + red[3][e] + bg[e];
    int e0 = 0; float l0 = l[0];
    for (int e = 1; e < 8; e++) if (l[e] > l0) { e0 = e; l0 = l[e]; }
    int e1 = -1; float l1 = -3.4e38f;
    for (int e = 0; e < 8; e++) if (e != e0 && l[e] > l1) { e1 = e; l1 = l[e]; }
    float w0 = 1.f / (1.f + __expf(l1 - l0));
    float w1 = 1.f - w0;
    int s0 = atomicAdd(&counts[e0], 1);
    int s1 = atomicAdd(&counts[e1], 1);
    tok_e[2 * t] = e0;     tok_slot[2 * t] = s0;     tok_w[2 * t] = w0;
    tok_e[2 * t + 1] = e1; tok_slot[2 * t + 1] = s1; tok_w[2 * t + 1] = w1;
  }
}

// ---------------- scan: expert offsets + 128-row tile map ----------------
__global__ void scan_kernel(const int* __restrict__ counts, int* __restrict__ offsets,
                            int* __restrict__ tm_e, int* __restrict__ tm_row0,
                            int* __restrict__ tm_nrow, int* __restrict__ ntp) {
  if (threadIdx.x != 0 || blockIdx.x != 0) return;
  int c[NE];
#pragma unroll
  for (int e = 0; e < NE; e++) c[e] = counts[e];
  int off = 0, nt = 0;
  for (int e = 0; e < NE; e++) {
    offsets[e] = off;
    for (int r = 0; r < c[e]; r += 128) {
      tm_e[nt] = e; tm_row0[nt] = off + r;
      tm_nrow[nt] = (c[e] - r < 128) ? (c[e] - r) : 128;
      nt++;
    }
    off += c[e];
  }
  *ntp = nt;
}

// ---------------- gather ----------------
__global__ __launch_bounds__(64) void gather_kernel(const float* __restrict__ x,
    const int* __restrict__ tok_e, const int* __restrict__ tok_slot,
    const float* __restrict__ tok_w, const int* __restrict__ offsets,
    unsigned short* __restrict__ Xe, int* __restrict__ pair_row, float* __restrict__ rw) {
  int pp = blockIdx.x, tid = threadIdx.x;
  int e = tok_e[pp];
  int row = offsets[e] + tok_slot[pp];
  int t = pp >> 1;
  const float* src = x + (size_t)t * DD + tid * 16;
  float4 v0 = *(const float4*)(src);
  float4 v1 = *(const float4*)(src + 4);
  float4 v2 = *(const float4*)(src + 8);
  float4 v3 = *(const float4*)(src + 12);
  unsigned int pk[8];
  pk[0] = f2bf(v0.x) | ((unsigned int)f2bf(v0.y) << 16);
  pk[1] = f2bf(v0.z) | ((unsigned int)f2bf(v0.w) << 16);
  pk[2] = f2bf(v1.x) | ((unsigned int)f2bf(v1.y) << 16);
  pk[3] = f2bf(v1.z) | ((unsigned int)f2bf(v1.w) << 16);
  pk[4] = f2bf(v2.x) | ((unsigned int)f2bf(v2.y) << 16);
  pk[5] = f2bf(v2.z) | ((unsigned int)f2bf(v2.w) << 16);
  pk[6] = f2bf(v3.x) | ((unsigned int)f2bf(v3.y) << 16);
  pk[7] = f2bf(v3.z) | ((unsigned int)f2bf(v3.w) << 16);
  unsigned short* dst = Xe + (size_t)row * DD + tid * 16;
  *(uint4*)(dst) = make_uint4(pk[0], pk[1], pk[2], pk[3]);
  *(uint4*)(dst + 8) = make_uint4(pk[4], pk[5], pk[6], pk[7]);
  if (tid == 0) { pair_row[pp] = row; rw[row] = tok_w[pp]; }
}

// Swizzle (BK=32, row = 64B = 4 chunks of 16B): chunk = kc ^ ((row>>1)&3).
// Source is pre-swizzled (rule #21): dest chunk cd holds logical chunk cd^((row>>1)&3);
// read applies same XOR -> logical chunk kc. 16 lanes (rows r..r+15) spread 2/bank-quad.

// ================= GEMM1: m97-shape, dual-B =================
// BM=128, BN=64-dual (Wa,W1), BK=32, 256 thr (4 waves 2Mx2N, wave 64x32-dual).
// LDS dbuf x (A[128][32] 8KB + Ba 4KB + Bu 4KB) = 32KB -> 3-4 blocks/CU.
__global__ __launch_bounds__(256) void gemm1_kernel(
    const unsigned short* __restrict__ Xe,
    const unsigned short* __restrict__ WaT,   // [E][H][D] bf16
    const unsigned short* __restrict__ W1T,
    const float* __restrict__ ba, const float* __restrict__ b1,
    unsigned short* __restrict__ h,
    const int* __restrict__ tm_e, const int* __restrict__ tm_row0,
    const int* __restrict__ tm_nrow, const int* __restrict__ ntp) {
  __shared__ unsigned short sm[2][8192];  // per buf: A @0 (4096 sh), Ba @4096, Bu @6144

  int work = blockIdx.x;
  int tile = work >> 6;
  if (tile >= *ntp) return;
  int n0 = (work & 63) << 6;
  int e = tm_e[tile], row0 = tm_row0[tile], nrow = tm_nrow[tile];

  int tid = threadIdx.x;
  int lane = tid & 63, wid = tid >> 6;
  int wm = wid >> 1, wn = wid & 1;     // 2M x 2N
  int fr = lane & 15, kc = lane >> 4;

  int srow = tid >> 2;
  int cd = tid & 3;
  int scl = (cd ^ ((srow >> 1) & 3)) << 3;        // pre-swizzled source chunk (elems)

  const unsigned short* pA0 = Xe + (size_t)(row0 + srow) * DD + scl;
  const unsigned short* pA1 = Xe + (size_t)(row0 + 64 + srow) * DD + scl;
  const unsigned short* pBa = WaT + ((size_t)e << 22) + (size_t)(n0 + srow) * DD + scl;
  const unsigned short* pBu = W1T + ((size_t)e << 22) + (size_t)(n0 + srow) * DD + scl;

  unsigned short* ldst = &sm[0][0] + (size_t)tid * 8;   // + buf*8192 (shorts)

  int aof[4], bof[2];
#pragma unroll
  for (int m = 0; m < 4; m++) {
    int r = wm * 64 + m * 16 + fr;                 // 0..127
    aof[m] = r * 64 + ((kc ^ ((r >> 1) & 3)) << 4);
  }
#pragma unroll
  for (int n = 0; n < 2; n++) {
    int r = wn * 32 + n * 16 + fr;                 // 0..63
    bof[n] = 8192 + r * 64 + ((kc ^ ((r >> 1) & 3)) << 4);
  }

  f32x4 accA[4][2], accU[4][2];
  f32x4 z = {0.f, 0.f, 0.f, 0.f};
#pragma unroll
  for (int m = 0; m < 4; m++)
#pragma unroll
    for (int n = 0; n < 2; n++) { accA[m][n] = z; accU[m][n] = z; }

  auto stage = [&](int T, int buf) {
    int koff = (T < G1_NT ? T : G1_NT - 1) << 5;
    unsigned short* L = ldst + buf * 8192;
    lds16(L, pA0 + koff);
    lds16(L + 2048, pA1 + koff);
    lds16(L + 4096, pBa + koff);
    lds16(L + 6144, pBu + koff);
  };

  stage(0, 0);
  __syncthreads();
  int buf = 0;
  for (int T = 0; T < G1_NT; ++T) {
    stage(T + 1, buf ^ 1);
    const char* lb = (const char*)&sm[0][0] + (buf << 14);
    bf16x8 a[4], bA[2], bU[2];
#pragma unroll
    for (int m = 0; m < 4; m++) a[m] = *(const bf16x8*)(lb + aof[m]);
#pragma unroll
    for (int n = 0; n < 2; n++) {
      bA[n] = *(const bf16x8*)(lb + bof[n]);
      bU[n] = *(const bf16x8*)(lb + bof[n] + 4096);
    }
#pragma unroll
    for (int m = 0; m < 4; m++)
#pragma unroll
      for (int n = 0; n < 2; n++) {
        accA[m][n] = __builtin_amdgcn_mfma_f32_16x16x32_bf16(a[m], bA[n], accA[m][n], 0, 0, 0);
        accU[m][n] = __builtin_amdgcn_mfma_f32_16x16x32_bf16(a[m], bU[n], accU[m][n], 0, 0, 0);
      }
    __syncthreads();
    buf ^= 1;
  }

  // epilogue: SwiGLU -> bf16 h
  int lr4 = kc * 4;
#pragma unroll
  for (int n = 0; n < 2; n++) {
    int col = n0 + wn * 32 + n * 16 + fr;
    float bav = ba[e * HH + col];
    float buv = b1[e * HH + col];
#pragma unroll
    for (int m = 0; m < 4; m++) {
#pragma unroll
      for (int j = 0; j < 4; j++) {
        int r = wm * 64 + m * 16 + lr4 + j;
        if (r < nrow) {
          float av = accA[m][n][j] + bav;
          float uv = accU[m][n][j] + buv;
          float s = __builtin_amdgcn_rcpf(1.f + __expf(-av));
          h[(size_t)(row0 + r) * HH + col] = f2bf(av * s * uv);
        }
      }
    }
  }
}

// ================= GEMM2: m97-shape =================
// BM=128, BN=128, BK=32, 256 thr (4 waves 2Mx2N, wave 64x64). Full K=4096.
__global__ __launch_bounds__(256) void gemm2_kernel(
    const unsigned short* __restrict__ hb,
    const unsigned short* __restrict__ W2T,   // [E][D][H] bf16
    const float* __restrict__ b2, const float* __restrict__ rw,
    float* __restrict__ contrib,
    const int* __restrict__ tm_e, const int* __restrict__ tm_row0,
    const int* __restrict__ tm_nrow, const int* __restrict__ ntp) {
  __shared__ unsigned short sm[2][8192];  // per buf: A @0, B @4096 (shorts)

  int work = blockIdx.x;
  int tile = work >> 3;
  if (tile >= *ntp) return;
  int n0 = (work & 7) << 7;
  int e = tm_e[tile], row0 = tm_row0[tile], nrow = tm_nrow[tile];

  int tid = threadIdx.x;
  int lane = tid & 63, wid = tid >> 6;
  int wm = wid >> 1, wn = wid & 1;
  int fr = lane & 15, kc = lane >> 4;

  int srow = tid >> 2;
  int cd = tid & 3;
  int scl = (cd ^ ((srow >> 1) & 3)) << 3;

  const unsigned short* pA0 = hb + (size_t)(row0 + srow) * HH + scl;
  const unsigned short* pA1 = hb + (size_t)(row0 + 64 + srow) * HH + scl;
  const unsigned short* pB0 = W2T + ((size_t)e << 22) + (size_t)(n0 + srow) * HH + scl;
  const unsigned short* pB1 = W2T + ((size_t)e << 22) + (size_t)(n0 + 64 + srow) * HH + scl;

  unsigned short* ldst = &sm[0][0] + (size_t)tid * 8;

  int aof[4], bof[4];
#pragma unroll
  for (int m = 0; m < 4; m++) {
    int r = wm * 64 + m * 16 + fr;
    aof[m] = r * 64 + ((kc ^ ((r >> 1) & 3)) << 4);
  }
#pragma unroll
  for (int n = 0; n < 4; n++) {
    int r = wn * 64 + n * 16 + fr;
    bof[n] = 8192 + r * 64 + ((kc ^ ((r >> 1) & 3)) << 4);
  }

  f32x4 acc[4][4];
  f32x4 z = {0.f, 0.f, 0.f, 0.f};
#pragma unroll
  for (int m = 0; m < 4; m++)
#pragma unroll
    for (int n = 0; n < 4; n++) acc[m][n] = z;

  auto stage = [&](int T, int buf) {
    int koff = (T < G2_NT ? T : G2_NT - 1) << 5;
    unsigned short* L = ldst + buf * 8192;
    lds16(L, pA0 + koff);
    lds16(L + 2048, pA1 + koff);
    lds16(L + 4096, pB0 + koff);
    lds16(L + 6144, pB1 + koff);
  };

  stage(0, 0);
  __syncthreads();
  int buf = 0;
  for (int T = 0; T < G2_NT; ++T) {
    stage(T + 1, buf ^ 1);
    const char* lb = (const char*)&sm[0][0] + (buf << 14);
    bf16x8 a[4], b[4];
#pragma unroll
    for (int m = 0; m < 4; m++) a[m] = *(const bf16x8*)(lb + aof[m]);
#pragma unroll
    for (int n = 0; n < 4; n++) b[n] = *(const bf16x8*)(lb + bof[n]);
#pragma unroll
    for (int m = 0; m < 4; m++)
#pragma unroll
      for (int n = 0; n < 4; n++)
        acc[m][n] = __builtin_amdgcn_mfma_f32_16x16x32_bf16(a[m], b[n], acc[m][n], 0, 0, 0);
    __syncthreads();
    buf ^= 1;
  }

  float b2v[4];
#pragma unroll
  for (int n = 0; n < 4; n++) b2v[n] = b2[e * DD + n0 + wn * 64 + n * 16 + fr];
  int lr4 = kc * 4;
#pragma unroll
  for (int m = 0; m < 4; m++) {
#pragma unroll
    for (int j = 0; j < 4; j++) {
      int r = wm * 64 + m * 16 + lr4 + j;
      if (r < nrow) {
        float wv = rw[row0 + r];
        float* dst = contrib + (size_t)(row0 + r) * DD + n0 + wn * 64 + fr;
#pragma unroll
        for (int n = 0; n < 4; n++)
          dst[n * 16] = wv * (acc[m][n][j] + b2v[n]);
      }
    }
  }
}

// ---------------- combine ----------------
__global__ __launch_bounds__(256) void combine_kernel(const float* __restrict__ contrib,
    const int* __restrict__ pair_row, float* __restrict__ out) {
  int t = blockIdx.x, tid = threadIdx.x;
  int r0 = pair_row[2 * t], r1 = pair_row[2 * t + 1];
  const float4* c0 = (const float4*)(contrib + (size_t)r0 * DD);
  const float4* c1 = (const float4*)(contrib + (size_t)r1 * DD);
  float4* o = (float4*)(out + (size_t)t * DD);
  float4 a = c0[tid], b = c1[tid];
  o[tid] = make_float4(a.x + b.x, a.y + b.y, a.z + b.z, a.w + b.w);
}

extern "C" void kernel_launch(void* const* d_in, const int* in_sizes, int n_in,
                              void* d_out, int out_size, void* d_ws, size_t ws_size,
                              hipStream_t stream) {
  const float* x  = (const float*)d_in[0];
  const float* Wg = (const float*)d_in[1];
  const float* bg = (const float*)d_in[2];
  const float* W1 = (const float*)d_in[3];
  const float* b1 = (const float*)d_in[4];
  const float* Wa = (const float*)d_in[5];
  const float* ba = (const float*)d_in[6];
  const float* W2 = (const float*)d_in[7];
  const float* b2 = (const float*)d_in[8];
  float* out = (float*)d_out;
  (void)in_sizes; (void)n_in; (void)out_size; (void)ws_size;

  char* p = (char*)d_ws;
  auto take = [&](size_t bytes) { char* r = p; p += (bytes + 255) & ~(size_t)255; return r; };
  unsigned short* WaT = (unsigned short*)take((size_t)NE * HH * DD * 2);
  unsigned short* W1T = (unsigned short*)take((size_t)NE * HH * DD * 2);
  unsigned short* W2T = (unsigned short*)take((size_t)NE * DD * HH * 2);
  unsigned short* Xe  = (unsigned short*)take((size_t)ROWCAP * DD * 2);
  unsigned short* hb  = (unsigned short*)take((size_t)ROWCAP * HH * 2);
  float* contrib      = (float*)take((size_t)ROWCAP * DD * 4);
  int* counts   = (int*)take(64);
  int* offsets  = (int*)take(64);
  int* tok_e    = (int*)take(PAIRS * 4);
  int* tok_slot = (int*)take(PAIRS * 4);
  float* tok_w  = (float*)take(PAIRS * 4);
  int* pair_row = (int*)take(PAIRS * 4);
  float* rw     = (float*)take(ROWCAP * 4);
  int* tm_e     = (int*)take(TCAP * 4);
  int* tm_row0  = (int*)take(TCAP * 4);
  int* tm_nrow  = (int*)take(TCAP * 4);
  int* ntp      = (int*)take(64);

  init_kernel<<<1, 64, 0, stream>>>(counts);
  transpose_kernel<<<3 * 8192, 256, 0, stream>>>(Wa, W1, W2, WaT, W1T, W2T);
  gate_kernel<<<TOKENS, 256, 0, stream>>>(x, Wg, bg, counts, tok_e, tok_slot, tok_w);
  scan_kernel<<<1, 64, 0, stream>>>(counts, offsets, tm_e, tm_row0, tm_nrow, ntp);
  gather_kernel<<<PAIRS, 64, 0, stream>>>(x, tok_e, tok_slot, tok_w, offsets, Xe, pair_row, rw);
  gemm1_kernel<<<TCAP * 64, 256, 0, stream>>>(Xe, WaT, W1T, ba, b1, hb, tm_e, tm_row0, tm_nrow, ntp);
  gemm2_kernel<<<TCAP * 8, 256, 0, stream>>>(hb, W2T, b2, rw, contrib, tm_e, tm_row0, tm_nrow, ntp);
  combine_kernel<<<TOKENS, 256, 0, stream>>>(contrib, pair_row, out);
}